// Round 3
// baseline (268.130 us; speedup 1.0000x reference)
//
#include <hip/hip_runtime.h>
#include <math.h>

// Problem constants
#define NVEC   65536      // B*H*W
#define CDIM   64
#define KBOOK  1024
#define NTOT   4194304    // B*C*H*W

// d_out layout (float32): [quantized_z: NTOT][quantized_z_st: NTOT][indices: NVEC][perplexity: 1]
// workspace: u64 keys[NVEC] @0 ; float se[KBOOK] @524288 ; int hist[KBOOK] @528384
// TRANSIENT scratch in d_out's quantized_z region (overwritten by scatter AFTER last read):
//   cand u32[NVEC][4] @out+0 (1MB) ; cbh bf16[1024][64] @out+1MB (128KB) ; cbl @out+1.125MB (128KB)
// Ordering: prep -> approx -> rescore -> scatter -> hist -> perp. Same stream: safe.

typedef __bf16 bf16x8 __attribute__((ext_vector_type(8)));
typedef float  f32x4  __attribute__((ext_vector_type(4)));

// prep: zero hist; exact se (pairwise 8-acc, rn intrinsics); pack codebook hi/lo bf16.
__global__ void prep_kernel(const float* __restrict__ cb, float* __restrict__ se,
                            int* __restrict__ hist, __bf16* __restrict__ cbh,
                            __bf16* __restrict__ cbl) {
    const int t = blockIdx.x * 256 + threadIdx.x;   // grid 4x256 -> t in [0,1024)
    hist[t] = 0;
    const float* row = cb + t * CDIM;
    float r[8];
#pragma unroll
    for (int j = 0; j < 8; ++j) r[j] = __fmul_rn(row[j], row[j]);
#pragma unroll
    for (int i = 8; i < 64; i += 8)
#pragma unroll
        for (int j = 0; j < 8; ++j) r[j] = __fadd_rn(r[j], __fmul_rn(row[i + j], row[i + j]));
    se[t] = __fadd_rn(__fadd_rn(__fadd_rn(r[0], r[1]), __fadd_rn(r[2], r[3])),
                      __fadd_rn(__fadd_rn(r[4], r[5]), __fadd_rn(r[6], r[7])));
    // hi/lo split: e = eh + el + O(2^-18 |e|); e - (float)eh is exact in fp32.
#pragma unroll
    for (int c = 0; c < 64; ++c) {
        float e = row[c];
        __bf16 h = (__bf16)e;
        cbh[t * 64 + c] = h;
        cbl[t * 64 + c] = (__bf16)(e - (float)h);
    }
}

// MFMA approx pass.  d'(n,k) = se_k + m.e_k, m = -2z, 3-term bf16 hi/lo.
// ROUND-2 RESTRUCTURE (latency-bound fix; was MfmaUtil 7.7 / VALUBusy 16 / 132us):
//  - each tile's 6-MFMA serial chain split into 2 independent 3-chains (accA/accB,
//    combined with 4 fp32 adds; approx-only rounding change, rescore stays exact)
//  - 2 tiles in flight per iteration  -> 4 independent MFMA chains per wave
//  - explicit depth-2 SW pipeline: slot pairs (a,b)/(c,d) ping-pong; next pair's
//    A-frags + se issued before current pair's MFMAs consume their operands.
// All slot registers are NAMED (no runtime-indexed arrays -> no scratch).
__launch_bounds__(256)
__attribute__((amdgpu_waves_per_eu(4, 4)))
__global__ void approx_kernel(const float* __restrict__ z, const __bf16* __restrict__ cbh,
                              const __bf16* __restrict__ cbl, const float* __restrict__ se,
                              unsigned int* __restrict__ cand) {
    const int tid = threadIdx.x;
    const int w = tid >> 6;           // wave in block
    const int l = tid & 63;           // lane
    const int la = l & 15;            // A-row offset / D-col (n) offset
    const int g  = l >> 4;            // lane group
    const int n = blockIdx.x * 64 + w * 16 + la;
    const int b = n >> 10, hw = n & 1023;
    const float* zb = z + (size_t)b * (CDIM * 1024) + hw;   // + c*1024

    // B-fragments (constant over the whole k-loop): z cols for this lane's n.
    bf16x8 mh0, ml0, mh1, ml1;
#pragma unroll
    for (int j = 0; j < 8; ++j) {
        {   // K-step 0: c in [0,32)
            float zc = zb[(g * 8 + j) * 1024];
            float m  = -2.0f * zc;
            __bf16 h = (__bf16)m;
            mh0[j] = h; ml0[j] = (__bf16)(m - (float)h);
        }
        {   // K-step 1: c in [32,64)
            float zc = zb[(32 + g * 8 + j) * 1024];
            float m  = -2.0f * zc;
            __bf16 h = (__bf16)m;
            mh1[j] = h; ml1[j] = (__bf16)(m - (float)h);
        }
    }

    float b1 = 3.4e38f, b2 = 3.4e38f;
    int   k1 = 0,       k2 = 0;
    const int kv = g * 4;             // D-row base for this lane

#define DECL_SLOT(s) bf16x8 ah0_##s, ah1_##s, al0_##s, al1_##s; f32x4 se_##s;
    DECL_SLOT(a) DECL_SLOT(b) DECL_SLOT(c) DECL_SLOT(d)
#undef DECL_SLOT

    // tile-slot load ('& 63' wraps the final overshoot prefetch -> harmless re-read)
#define LOADT(s, ttv) { const int k0_ = ((ttv) & 63) * 16;               \
        const size_t ab_ = (size_t)((k0_ + la) << 6) + 8 * g;            \
        ah0_##s = *(const bf16x8*)(cbh + ab_);                           \
        ah1_##s = *(const bf16x8*)(cbh + ab_ + 32);                      \
        al0_##s = *(const bf16x8*)(cbl + ab_);                           \
        al1_##s = *(const bf16x8*)(cbl + ab_ + 32);                      \
        se_##s  = *(const f32x4*)(se + k0_ + kv); }

    // top-2 insert (strict <, ascending k: first-min kept on approx ties)
#define INS1(d_, kt_) { const bool c1 = (d_) < b1, c2 = (d_) < b2;       \
        b2 = c1 ? b1 : (c2 ? (d_) : b2);  k2 = c1 ? k1 : (c2 ? (kt_) : k2); \
        b1 = c1 ? (d_) : b1;              k1 = c1 ? (kt_) : k1; }

    // 2 independent 3-chains, issue-interleaved A/B
#define COMPT(s, ttv) { const int k0_ = (ttv) * 16;                      \
        f32x4 aA = se_##s; f32x4 aB = {0.f, 0.f, 0.f, 0.f};              \
        aA = __builtin_amdgcn_mfma_f32_16x16x32_bf16(ah0_##s, mh0, aA, 0, 0, 0); \
        aB = __builtin_amdgcn_mfma_f32_16x16x32_bf16(ah1_##s, mh1, aB, 0, 0, 0); \
        aA = __builtin_amdgcn_mfma_f32_16x16x32_bf16(al0_##s, mh0, aA, 0, 0, 0); \
        aB = __builtin_amdgcn_mfma_f32_16x16x32_bf16(al1_##s, mh1, aB, 0, 0, 0); \
        aA = __builtin_amdgcn_mfma_f32_16x16x32_bf16(ah0_##s, ml0, aA, 0, 0, 0); \
        aB = __builtin_amdgcn_mfma_f32_16x16x32_bf16(ah1_##s, ml1, aB, 0, 0, 0); \
        { const float d0_ = aA[0] + aB[0]; INS1(d0_, k0_ + kv)     }     \
        { const float d1_ = aA[1] + aB[1]; INS1(d1_, k0_ + kv + 1) }     \
        { const float d2_ = aA[2] + aB[2]; INS1(d2_, k0_ + kv + 2) }     \
        { const float d3_ = aA[3] + aB[3]; INS1(d3_, k0_ + kv + 3) } }

    LOADT(a, 0) LOADT(b, 1)
    for (int tt = 0; tt < 64; tt += 4) {
        LOADT(c, tt + 2) LOADT(d, tt + 3)
        COMPT(a, tt)     COMPT(b, tt + 1)
        LOADT(a, tt + 4) LOADT(b, tt + 5)
        COMPT(c, tt + 2) COMPT(d, tt + 3)
    }
#undef LOADT
#undef INS1
#undef COMPT

    cand[n * 4 + g] = (unsigned int)k1 | ((unsigned int)k2 << 16);
}

// Exact rescore of the 8 candidates per n.  Bit-identical chain to the reference:
// zx = 2z; a_k = ascending-c fmaf chain; sx = pairwise 8-acc of fl(z^2);
// d = fl(fl(sx + se_k) - a_k).  Min via ordered-u64 key (d bits || k): first-min semantics.
__global__ void rescore_kernel(const float* __restrict__ z, const float* __restrict__ cb,
                               const float* __restrict__ se,
                               const unsigned int* __restrict__ cand,
                               unsigned long long* __restrict__ keys) {
    const int n = blockIdx.x * 256 + threadIdx.x;   // grid 256x256
    int ks[8];
#pragma unroll
    for (int g = 0; g < 4; ++g) {
        const unsigned int p = cand[n * 4 + g];
        ks[2 * g]     = (int)(p & 0xFFFFu);
        ks[2 * g + 1] = (int)(p >> 16);
    }
    const int b = n >> 10, hw = n & 1023;
    const float* zb = z + (size_t)b * (CDIM * 1024) + hw;

    float zx[64], r[8];
#pragma unroll
    for (int j = 0; j < 8; ++j) {
        const float zc = zb[j * 1024];
        zx[j] = zc + zc;
        r[j] = __fmul_rn(zc, zc);
    }
#pragma unroll
    for (int c = 8; c < 64; ++c) {
        const float zc = zb[c * 1024];
        zx[c] = zc + zc;
        r[c & 7] = __fadd_rn(r[c & 7], __fmul_rn(zc, zc));
    }
    const float sx = __fadd_rn(__fadd_rn(__fadd_rn(r[0], r[1]), __fadd_rn(r[2], r[3])),
                               __fadd_rn(__fadd_rn(r[4], r[5]), __fadd_rn(r[6], r[7])));

    float a[8];
#pragma unroll
    for (int i = 0; i < 8; ++i) a[i] = 0.0f;
    const float4* cb4 = (const float4*)cb;
#pragma unroll
    for (int q = 0; q < 16; ++q) {               // c = 4q .. 4q+3, ascending per chain
#pragma unroll
        for (int i = 0; i < 8; ++i) {
            const float4 ev = cb4[ks[i] * 16 + q];
            a[i] = fmaf(zx[4 * q],     ev.x, a[i]);
            a[i] = fmaf(zx[4 * q + 1], ev.y, a[i]);
            a[i] = fmaf(zx[4 * q + 2], ev.z, a[i]);
            a[i] = fmaf(zx[4 * q + 3], ev.w, a[i]);
        }
    }
    unsigned long long best = ~0ull;
#pragma unroll
    for (int i = 0; i < 8; ++i) {
        const float d = __fsub_rn(__fadd_rn(sx, se[ks[i]]), a[i]);
        unsigned int ob = __float_as_uint(d);
        ob = (ob & 0x80000000u) ? ~ob : (ob | 0x80000000u);
        const unsigned long long key = ((unsigned long long)ob << 32) | (unsigned int)ks[i];
        if (key < best) best = key;
    }
    keys[n] = best;    // single writer: plain store
}

// quantized_z = cb[idx]; quantized_z_st = fl(z + fl(q - z)); float4-vectorized
__global__ void scatter_kernel(const float* __restrict__ z, const float* __restrict__ cb,
                               const unsigned long long* __restrict__ keys,
                               float* __restrict__ out) {
    const int o = (blockIdx.x * 256 + threadIdx.x) * 4;    // [0, NTOT), step 4
    const int b = o >> 16, c = (o >> 10) & 63, hw = o & 1023;
    const int n = (b << 10) | hw;
    float q[4];
#pragma unroll
    for (int j = 0; j < 4; ++j) {
        const int k = (int)(keys[n + j] & 0xFFFFFFFFu);
        q[j] = cb[k * CDIM + c];
    }
    const float4 zv = *(const float4*)(z + o);
    *(float4*)(out + o) = make_float4(q[0], q[1], q[2], q[3]);
    float4 st;
    st.x = __fadd_rn(zv.x, __fsub_rn(q[0], zv.x));
    st.y = __fadd_rn(zv.y, __fsub_rn(q[1], zv.y));
    st.z = __fadd_rn(zv.z, __fsub_rn(q[2], zv.z));
    st.w = __fadd_rn(zv.w, __fsub_rn(q[3], zv.w));
    *(float4*)(out + NTOT + o) = st;
}

// histogram + indices-as-float
__global__ void hist_kernel(const unsigned long long* __restrict__ keys, int* __restrict__ hist,
                            float* __restrict__ outIdxF) {
    __shared__ int lh[KBOOK];
    for (int i = threadIdx.x; i < KBOOK; i += 256) lh[i] = 0;
    __syncthreads();
    const int n = blockIdx.x * 256 + threadIdx.x;          // grid = 256 blocks
    const int k = (int)(keys[n] & 0xFFFFFFFFu);
    outIdxF[n] = (float)k;
    atomicAdd(&lh[k], 1);
    __syncthreads();
    for (int i = threadIdx.x; i < KBOOK; i += 256)
        if (lh[i]) atomicAdd(&hist[i], lh[i]);
}

__global__ void perp_kernel(const int* __restrict__ hist, float* __restrict__ out) {
    __shared__ double partial[16];
    const int t = threadIdx.x;  // 1024 threads
    const int c = hist[t];
    double term = 0.0;
    if (c > 0) { double p = (double)c / (double)NVEC; term = p * log(p); }
    for (int off = 32; off > 0; off >>= 1) term += __shfl_down(term, off);
    if ((t & 63) == 0) partial[t >> 6] = term;
    __syncthreads();
    if (t == 0) {
        double s = 0.0;
        for (int i = 0; i < 16; ++i) s += partial[i];
        out[2 * NTOT + NVEC] = (float)exp(-s);
    }
}

extern "C" void kernel_launch(void* const* d_in, const int* in_sizes, int n_in,
                              void* d_out, int out_size, void* d_ws, size_t ws_size,
                              hipStream_t stream) {
    const float* z  = (const float*)d_in[0];   // [64,64,32,32]
    const float* cb = (const float*)d_in[1];   // [1024,64]
    float* out = (float*)d_out;

    char* ws = (char*)d_ws;
    unsigned long long* keys = (unsigned long long*)(ws + 0);
    float* se   = (float*)(ws + 524288);
    int*   hist = (int*)(ws + 528384);

    // Transient scratch inside d_out's quantized_z region (overwritten by scatter later).
    char* outB = (char*)d_out;
    unsigned int* cand = (unsigned int*)(outB);                         // 1 MB
    __bf16* cbh = (__bf16*)(outB + (1 << 20));                          // 128 KB
    __bf16* cbl = (__bf16*)(outB + (1 << 20) + (128 << 10));            // 128 KB

    prep_kernel<<<4, 256, 0, stream>>>(cb, se, hist, cbh, cbl);
    approx_kernel<<<NVEC / 64, 256, 0, stream>>>(z, cbh, cbl, se, cand);
    rescore_kernel<<<NVEC / 256, 256, 0, stream>>>(z, cb, se, cand, keys);
    scatter_kernel<<<NTOT / 1024, 256, 0, stream>>>(z, cb, keys, out);
    hist_kernel<<<NVEC / 256, 256, 0, stream>>>(keys, hist, out + 2 * NTOT);
    perp_kernel<<<1, 1024, 0, stream>>>(hist, out);
}

// Round 4
// 182.146 us; speedup vs baseline: 1.4721x; 1.4721x over previous
//
#include <hip/hip_runtime.h>
#include <math.h>

// Problem constants
#define NVEC   65536      // B*H*W
#define CDIM   64
#define KBOOK  1024
#define NTOT   4194304    // B*C*H*W

// d_out layout (float32): [quantized_z: NTOT][quantized_z_st: NTOT][indices: NVEC][perplexity: 1]
// workspace: u64 keys[NVEC] @0 ; float se[KBOOK] @524288 ; int hist[KBOOK] @528384
// TRANSIENT scratch in d_out's quantized_z region (overwritten by scatter AFTER last read):
//   cand u32[NVEC][4] @out+0 (1MB) ; cbT bf16 fragment-ordered codebook @out+1MB (256KB)
// Ordering: prep -> approx -> rescore -> scatter -> hist -> perp. Same stream: safe.
//
// cbT layout (ROUND-3: coalescing fix): per 16-k tile tt a contiguous 4KB block of
// 4 sub-blocks [ah0|ah1|al0|al1], each 512 bf16 stored in MFMA-fragment lane order:
//   sub[lane*8 + j] = value for lane's A-fragment element j.
// A-frag mapping (16x16x32): lane l holds A[l&15][8*(l>>4)+j]; ah0/al0 = cols 0..31
// (hi/lo), ah1/al1 = cols 32..63.  => every A-load is ONE fully-contiguous 1KB
// global_load_dwordx4 (was: 16-discontiguous-line gather, stride 128B -> TA serialized).

typedef __bf16 bf16x8 __attribute__((ext_vector_type(8)));
typedef float  f32x4  __attribute__((ext_vector_type(4)));

// prep: zero hist; exact se (pairwise 8-acc, rn intrinsics); pack fragment-ordered hi/lo codebook.
__global__ void prep_kernel(const float* __restrict__ cb, float* __restrict__ se,
                            int* __restrict__ hist, __bf16* __restrict__ cbT) {
    const int t = blockIdx.x * 256 + threadIdx.x;   // grid 4x256 -> t = codebook row k
    hist[t] = 0;
    const float* row = cb + t * CDIM;
    float r[8];
#pragma unroll
    for (int j = 0; j < 8; ++j) r[j] = __fmul_rn(row[j], row[j]);
#pragma unroll
    for (int i = 8; i < 64; i += 8)
#pragma unroll
        for (int j = 0; j < 8; ++j) r[j] = __fadd_rn(r[j], __fmul_rn(row[i + j], row[i + j]));
    se[t] = __fadd_rn(__fadd_rn(__fadd_rn(r[0], r[1]), __fadd_rn(r[2], r[3])),
                      __fadd_rn(__fadd_rn(r[4], r[5]), __fadd_rn(r[6], r[7])));
    // hi/lo split: e = eh + el + O(2^-18 |e|); e - (float)eh is exact in fp32.
    const int tt = t >> 4, la = t & 15;
    __bf16* tb = cbT + (size_t)tt * 2048;          // 4KB tile block (bf16 units)
#pragma unroll
    for (int g = 0; g < 4; ++g)
#pragma unroll
        for (int j = 0; j < 8; ++j) {
            const float e0 = row[8 * g + j];        // c in [0,32)
            const float e1 = row[32 + 8 * g + j];   // c in [32,64)
            const __bf16 h0 = (__bf16)e0, h1 = (__bf16)e1;
            const int lo8 = (g * 16 + la) * 8 + j;  // lane*8 + j
            tb[lo8]              = h0;                          // ah0
            tb[512 + lo8]        = h1;                          // ah1
            tb[1024 + lo8]       = (__bf16)(e0 - (float)h0);    // al0
            tb[1536 + lo8]       = (__bf16)(e1 - (float)h1);    // al1
        }
}

// MFMA approx pass.  d'(n,k) = se_k + m.e_k, m = -2z, 3-term bf16 hi/lo
// (mh*eh + mh*el + ml*eh; dropped terms ~1e-6 abs vs distance spacing ~4e-3).
// B-frag: lane holds B[8*(l>>4)+j][l&15]; D: col = l&15 (n), row = 4*(l>>4)+reg (k).
// Per-lane: 4 k-rows x 1 n over 64 tiles => top-2 over a disjoint 256-k subset;
// union over 4 lane-groups = 8 cand/n (exact argmin excluded only if >=2
// same-subset competitors within ~2e-6: P ~ 5e-3 over all n; rescore is exact).
// ROUND-3: coalesced fragment-ordered A-loads (1 addr-add + imm offsets per tile);
// depth-2 ping-pong prefetch, 2 slots (~90 live VGPR -> no spills under the 128 cap).
__launch_bounds__(256)
__attribute__((amdgpu_waves_per_eu(4, 4)))
__global__ void approx_kernel(const float* __restrict__ z, const __bf16* __restrict__ cbT,
                              const float* __restrict__ se,
                              unsigned int* __restrict__ cand) {
    const int tid = threadIdx.x;
    const int w = tid >> 6;           // wave in block
    const int l = tid & 63;           // lane
    const int la = l & 15;            // D-col (n) offset / A-row offset
    const int g  = l >> 4;            // lane group
    const int n = blockIdx.x * 64 + w * 16 + la;
    const int b = n >> 10, hw = n & 1023;
    const float* zb = z + (size_t)b * (CDIM * 1024) + hw;   // + c*1024

    // B-fragments (constant over the whole k-loop): z cols for this lane's n.
    bf16x8 mh0, ml0, mh1, ml1;
#pragma unroll
    for (int j = 0; j < 8; ++j) {
        {   // K-step 0: c in [0,32)
            float zc = zb[(g * 8 + j) * 1024];
            float m  = -2.0f * zc;
            __bf16 h = (__bf16)m;
            mh0[j] = h; ml0[j] = (__bf16)(m - (float)h);
        }
        {   // K-step 1: c in [32,64)
            float zc = zb[(32 + g * 8 + j) * 1024];
            float m  = -2.0f * zc;
            __bf16 h = (__bf16)m;
            mh1[j] = h; ml1[j] = (__bf16)(m - (float)h);
        }
    }

    float b1 = 3.4e38f, b2 = 3.4e38f;
    int   k1 = 0,       k2 = 0;
    const int kv = g * 4;                          // D-row base for this lane
    const __bf16* tbase = cbT + (size_t)l * 8;     // lane offset inside each sub-block

#define DECL_SLOT(s) bf16x8 ah0_##s, ah1_##s, al0_##s, al1_##s; f32x4 se_##s;
    DECL_SLOT(a) DECL_SLOT(b)
#undef DECL_SLOT

    // tile-slot load: 4 contiguous 1KB wave-loads + 16B se ('& 63' wraps overshoot)
#define LOADT(s, ttv) { const int t_ = (ttv) & 63;                       \
        const __bf16* p_ = tbase + (size_t)t_ * 2048;                    \
        ah0_##s = *(const bf16x8*)(p_);                                  \
        ah1_##s = *(const bf16x8*)(p_ + 512);                            \
        al0_##s = *(const bf16x8*)(p_ + 1024);                           \
        al1_##s = *(const bf16x8*)(p_ + 1536);                           \
        se_##s  = *(const f32x4*)(se + t_ * 16 + kv); }

    // top-2 insert (strict <, ascending k: first-min kept on approx ties)
#define INS1(d_, kt_) { const bool c1 = (d_) < b1, c2 = (d_) < b2;       \
        b2 = c1 ? b1 : (c2 ? (d_) : b2);  k2 = c1 ? k1 : (c2 ? (kt_) : k2); \
        b1 = c1 ? (d_) : b1;              k1 = c1 ? (kt_) : k1; }

    // 2 independent 3-chains, issue-interleaved A/B
#define COMPT(s, ttv) { const int k0_ = (ttv) * 16;                      \
        f32x4 aA = se_##s; f32x4 aB = {0.f, 0.f, 0.f, 0.f};              \
        aA = __builtin_amdgcn_mfma_f32_16x16x32_bf16(ah0_##s, mh0, aA, 0, 0, 0); \
        aB = __builtin_amdgcn_mfma_f32_16x16x32_bf16(ah1_##s, mh1, aB, 0, 0, 0); \
        aA = __builtin_amdgcn_mfma_f32_16x16x32_bf16(al0_##s, mh0, aA, 0, 0, 0); \
        aB = __builtin_amdgcn_mfma_f32_16x16x32_bf16(al1_##s, mh1, aB, 0, 0, 0); \
        aA = __builtin_amdgcn_mfma_f32_16x16x32_bf16(ah0_##s, ml0, aA, 0, 0, 0); \
        aB = __builtin_amdgcn_mfma_f32_16x16x32_bf16(ah1_##s, ml1, aB, 0, 0, 0); \
        { const float d0_ = aA[0] + aB[0]; INS1(d0_, k0_ + kv)     }     \
        { const float d1_ = aA[1] + aB[1]; INS1(d1_, k0_ + kv + 1) }     \
        { const float d2_ = aA[2] + aB[2]; INS1(d2_, k0_ + kv + 2) }     \
        { const float d3_ = aA[3] + aB[3]; INS1(d3_, k0_ + kv + 3) } }

    LOADT(a, 0)
    for (int tt = 0; tt < 64; tt += 2) {
        LOADT(b, tt + 1)
        COMPT(a, tt)
        LOADT(a, tt + 2)
        COMPT(b, tt + 1)
    }
#undef LOADT
#undef INS1
#undef COMPT

    cand[n * 4 + g] = (unsigned int)k1 | ((unsigned int)k2 << 16);
}

// Exact rescore of the 8 candidates per n.  Bit-identical chain to the reference:
// zx = 2z; a_k = ascending-c fmaf chain; sx = pairwise 8-acc of fl(z^2);
// d = fl(fl(sx + se_k) - a_k).  Min via ordered-u64 key (d bits || k): first-min semantics.
__global__ void rescore_kernel(const float* __restrict__ z, const float* __restrict__ cb,
                               const float* __restrict__ se,
                               const unsigned int* __restrict__ cand,
                               unsigned long long* __restrict__ keys) {
    const int n = blockIdx.x * 256 + threadIdx.x;   // grid 256x256
    int ks[8];
#pragma unroll
    for (int g = 0; g < 4; ++g) {
        const unsigned int p = cand[n * 4 + g];
        ks[2 * g]     = (int)(p & 0xFFFFu);
        ks[2 * g + 1] = (int)(p >> 16);
    }
    const int b = n >> 10, hw = n & 1023;
    const float* zb = z + (size_t)b * (CDIM * 1024) + hw;

    float zx[64], r[8];
#pragma unroll
    for (int j = 0; j < 8; ++j) {
        const float zc = zb[j * 1024];
        zx[j] = zc + zc;
        r[j] = __fmul_rn(zc, zc);
    }
#pragma unroll
    for (int c = 8; c < 64; ++c) {
        const float zc = zb[c * 1024];
        zx[c] = zc + zc;
        r[c & 7] = __fadd_rn(r[c & 7], __fmul_rn(zc, zc));
    }
    const float sx = __fadd_rn(__fadd_rn(__fadd_rn(r[0], r[1]), __fadd_rn(r[2], r[3])),
                               __fadd_rn(__fadd_rn(r[4], r[5]), __fadd_rn(r[6], r[7])));

    float a[8];
#pragma unroll
    for (int i = 0; i < 8; ++i) a[i] = 0.0f;
    const float4* cb4 = (const float4*)cb;
#pragma unroll
    for (int q = 0; q < 16; ++q) {               // c = 4q .. 4q+3, ascending per chain
#pragma unroll
        for (int i = 0; i < 8; ++i) {
            const float4 ev = cb4[ks[i] * 16 + q];
            a[i] = fmaf(zx[4 * q],     ev.x, a[i]);
            a[i] = fmaf(zx[4 * q + 1], ev.y, a[i]);
            a[i] = fmaf(zx[4 * q + 2], ev.z, a[i]);
            a[i] = fmaf(zx[4 * q + 3], ev.w, a[i]);
        }
    }
    unsigned long long best = ~0ull;
#pragma unroll
    for (int i = 0; i < 8; ++i) {
        const float d = __fsub_rn(__fadd_rn(sx, se[ks[i]]), a[i]);
        unsigned int ob = __float_as_uint(d);
        ob = (ob & 0x80000000u) ? ~ob : (ob | 0x80000000u);
        const unsigned long long key = ((unsigned long long)ob << 32) | (unsigned int)ks[i];
        if (key < best) best = key;
    }
    keys[n] = best;    // single writer: plain store
}

// quantized_z = cb[idx]; quantized_z_st = fl(z + fl(q - z)); float4-vectorized
__global__ void scatter_kernel(const float* __restrict__ z, const float* __restrict__ cb,
                               const unsigned long long* __restrict__ keys,
                               float* __restrict__ out) {
    const int o = (blockIdx.x * 256 + threadIdx.x) * 4;    // [0, NTOT), step 4
    const int b = o >> 16, c = (o >> 10) & 63, hw = o & 1023;
    const int n = (b << 10) | hw;
    float q[4];
#pragma unroll
    for (int j = 0; j < 4; ++j) {
        const int k = (int)(keys[n + j] & 0xFFFFFFFFu);
        q[j] = cb[k * CDIM + c];
    }
    const float4 zv = *(const float4*)(z + o);
    *(float4*)(out + o) = make_float4(q[0], q[1], q[2], q[3]);
    float4 st;
    st.x = __fadd_rn(zv.x, __fsub_rn(q[0], zv.x));
    st.y = __fadd_rn(zv.y, __fsub_rn(q[1], zv.y));
    st.z = __fadd_rn(zv.z, __fsub_rn(q[2], zv.z));
    st.w = __fadd_rn(zv.w, __fsub_rn(q[3], zv.w));
    *(float4*)(out + NTOT + o) = st;
}

// histogram + indices-as-float
__global__ void hist_kernel(const unsigned long long* __restrict__ keys, int* __restrict__ hist,
                            float* __restrict__ outIdxF) {
    __shared__ int lh[KBOOK];
    for (int i = threadIdx.x; i < KBOOK; i += 256) lh[i] = 0;
    __syncthreads();
    const int n = blockIdx.x * 256 + threadIdx.x;          // grid = 256 blocks
    const int k = (int)(keys[n] & 0xFFFFFFFFu);
    outIdxF[n] = (float)k;
    atomicAdd(&lh[k], 1);
    __syncthreads();
    for (int i = threadIdx.x; i < KBOOK; i += 256)
        if (lh[i]) atomicAdd(&hist[i], lh[i]);
}

__global__ void perp_kernel(const int* __restrict__ hist, float* __restrict__ out) {
    __shared__ double partial[16];
    const int t = threadIdx.x;  // 1024 threads
    const int c = hist[t];
    double term = 0.0;
    if (c > 0) { double p = (double)c / (double)NVEC; term = p * log(p); }
    for (int off = 32; off > 0; off >>= 1) term += __shfl_down(term, off);
    if ((t & 63) == 0) partial[t >> 6] = term;
    __syncthreads();
    if (t == 0) {
        double s = 0.0;
        for (int i = 0; i < 16; ++i) s += partial[i];
        out[2 * NTOT + NVEC] = (float)exp(-s);
    }
}

extern "C" void kernel_launch(void* const* d_in, const int* in_sizes, int n_in,
                              void* d_out, int out_size, void* d_ws, size_t ws_size,
                              hipStream_t stream) {
    const float* z  = (const float*)d_in[0];   // [64,64,32,32]
    const float* cb = (const float*)d_in[1];   // [1024,64]
    float* out = (float*)d_out;

    char* ws = (char*)d_ws;
    unsigned long long* keys = (unsigned long long*)(ws + 0);
    float* se   = (float*)(ws + 524288);
    int*   hist = (int*)(ws + 528384);

    // Transient scratch inside d_out's quantized_z region (overwritten by scatter later).
    char* outB = (char*)d_out;
    unsigned int* cand = (unsigned int*)(outB);                         // 1 MB
    __bf16* cbT = (__bf16*)(outB + (1 << 20));                          // 256 KB

    prep_kernel<<<4, 256, 0, stream>>>(cb, se, hist, cbT);
    approx_kernel<<<NVEC / 64, 256, 0, stream>>>(z, cbT, se, cand);
    rescore_kernel<<<NVEC / 256, 256, 0, stream>>>(z, cb, se, cand, keys);
    scatter_kernel<<<NTOT / 1024, 256, 0, stream>>>(z, cb, keys, out);
    hist_kernel<<<NVEC / 256, 256, 0, stream>>>(keys, hist, out + 2 * NTOT);
    perp_kernel<<<1, 1024, 0, stream>>>(hist, out);
}

// Round 5
// 173.599 us; speedup vs baseline: 1.5445x; 1.0492x over previous
//
#include <hip/hip_runtime.h>
#include <math.h>

// Problem constants
#define NVEC   65536      // B*H*W
#define CDIM   64
#define KBOOK  1024
#define NTOT   4194304    // B*C*H*W

// d_out layout (float32): [quantized_z: NTOT][quantized_z_st: NTOT][indices: NVEC][perplexity: 1]
// workspace: u64 keys[NVEC] @0 ; float se[KBOOK] @524288 ; int hist[KBOOK] @528384
// TRANSIENT scratch in d_out's quantized_z region (overwritten by scatter AFTER last read):
//   cand u32[NVEC][4] @out+0 (1MB) ; cbT bf16 fragment-ordered codebook @out+1MB (256KB)
// Ordering: prep -> approx -> rescore(+hist+idx) -> scatter(+perp). 4 launches (was 6).
//
// cbT layout (coalescing fix, round 3): per 16-k tile tt a contiguous 4KB block of
// 4 sub-blocks [ah0|ah1|al0|al1], each 512 bf16 in MFMA-fragment lane order:
//   sub[lane*8 + j] = lane's A-fragment element j.  => every A-load is ONE fully
// contiguous 1KB wave load (global_load_dwordx4 at base + imm offset).

typedef __bf16 bf16x8 __attribute__((ext_vector_type(8)));
typedef float  f32x4  __attribute__((ext_vector_type(4)));

// prep: zero hist; exact se (pairwise 8-acc, rn intrinsics); pack fragment-ordered hi/lo codebook.
__global__ void prep_kernel(const float* __restrict__ cb, float* __restrict__ se,
                            int* __restrict__ hist, __bf16* __restrict__ cbT) {
    const int t = blockIdx.x * 256 + threadIdx.x;   // grid 4x256 -> t = codebook row k
    hist[t] = 0;
    const float* row = cb + t * CDIM;
    float r[8];
#pragma unroll
    for (int j = 0; j < 8; ++j) r[j] = __fmul_rn(row[j], row[j]);
#pragma unroll
    for (int i = 8; i < 64; i += 8)
#pragma unroll
        for (int j = 0; j < 8; ++j) r[j] = __fadd_rn(r[j], __fmul_rn(row[i + j], row[i + j]));
    se[t] = __fadd_rn(__fadd_rn(__fadd_rn(r[0], r[1]), __fadd_rn(r[2], r[3])),
                      __fadd_rn(__fadd_rn(r[4], r[5]), __fadd_rn(r[6], r[7])));
    // hi/lo split: e = eh + el + O(2^-18 |e|); e - (float)eh is exact in fp32.
    const int tt = t >> 4, la = t & 15;
    __bf16* tb = cbT + (size_t)tt * 2048;          // 4KB tile block (bf16 units)
#pragma unroll
    for (int g = 0; g < 4; ++g)
#pragma unroll
        for (int j = 0; j < 8; ++j) {
            const float e0 = row[8 * g + j];        // c in [0,32)
            const float e1 = row[32 + 8 * g + j];   // c in [32,64)
            const __bf16 h0 = (__bf16)e0, h1 = (__bf16)e1;
            const int lo8 = (g * 16 + la) * 8 + j;  // lane*8 + j
            tb[lo8]              = h0;                          // ah0
            tb[512 + lo8]        = h1;                          // ah1
            tb[1024 + lo8]       = (__bf16)(e0 - (float)h0);    // al0
            tb[1536 + lo8]       = (__bf16)(e1 - (float)h1);    // al1
        }
}

// MFMA approx pass.  d'(n,k) = se_k + m.e_k, m = -2z, 3-term bf16 hi/lo
// (mh*eh + mh*el + ml*eh; dropped terms ~1e-6 abs vs distance spacing ~4e-3).
// B-frag: lane holds B[8*(l>>4)+j][l&15]; D: col = l&15 (n), row = 4*(l>>4)+reg (k).
// Per-lane: 4 k-rows x 1 n over 64 tiles => top-2 over a disjoint 256-k subset;
// union over 4 lane-groups = 8 cand/n; rescore is exact.
// ROUND-4: depth-4 slot pipeline (round-2 schedule, now spill-free: round-3's
// base+imm addressing cut live set to ~92 VGPR < 128 cap).  Latency-bound fix:
// prefetch distance 2 tiles (~240+ cyc) >= L2 latency (~200 cyc).
__launch_bounds__(256)
__attribute__((amdgpu_waves_per_eu(4, 4)))
__global__ void approx_kernel(const float* __restrict__ z, const __bf16* __restrict__ cbT,
                              const float* __restrict__ se,
                              unsigned int* __restrict__ cand) {
    const int tid = threadIdx.x;
    const int w = tid >> 6;           // wave in block
    const int l = tid & 63;           // lane
    const int la = l & 15;            // D-col (n) offset / A-row offset
    const int g  = l >> 4;            // lane group
    const int n = blockIdx.x * 64 + w * 16 + la;
    const int b = n >> 10, hw = n & 1023;
    const float* zb = z + (size_t)b * (CDIM * 1024) + hw;   // + c*1024

    // B-fragments (constant over the whole k-loop): z cols for this lane's n.
    bf16x8 mh0, ml0, mh1, ml1;
#pragma unroll
    for (int j = 0; j < 8; ++j) {
        {   // K-step 0: c in [0,32)
            float zc = zb[(g * 8 + j) * 1024];
            float m  = -2.0f * zc;
            __bf16 h = (__bf16)m;
            mh0[j] = h; ml0[j] = (__bf16)(m - (float)h);
        }
        {   // K-step 1: c in [32,64)
            float zc = zb[(32 + g * 8 + j) * 1024];
            float m  = -2.0f * zc;
            __bf16 h = (__bf16)m;
            mh1[j] = h; ml1[j] = (__bf16)(m - (float)h);
        }
    }

    float b1 = 3.4e38f, b2 = 3.4e38f;
    int   k1 = 0,       k2 = 0;
    const int kv = g * 4;                          // D-row base for this lane
    const __bf16* tbase = cbT + (size_t)l * 8;     // lane offset inside each sub-block

#define DECL_SLOT(s) bf16x8 ah0_##s, ah1_##s, al0_##s, al1_##s; f32x4 se_##s;
    DECL_SLOT(a) DECL_SLOT(b) DECL_SLOT(c) DECL_SLOT(d)
#undef DECL_SLOT

    // tile-slot load: 4 contiguous 1KB wave-loads + 16B se ('& 63' wraps overshoot)
#define LOADT(s, ttv) { const int t_ = (ttv) & 63;                       \
        const __bf16* p_ = tbase + (size_t)t_ * 2048;                    \
        ah0_##s = *(const bf16x8*)(p_);                                  \
        ah1_##s = *(const bf16x8*)(p_ + 512);                            \
        al0_##s = *(const bf16x8*)(p_ + 1024);                           \
        al1_##s = *(const bf16x8*)(p_ + 1536);                           \
        se_##s  = *(const f32x4*)(se + t_ * 16 + kv); }

    // top-2 insert (strict <, ascending k: first-min kept on approx ties)
#define INS1(d_, kt_) { const bool c1 = (d_) < b1, c2 = (d_) < b2;       \
        b2 = c1 ? b1 : (c2 ? (d_) : b2);  k2 = c1 ? k1 : (c2 ? (kt_) : k2); \
        b1 = c1 ? (d_) : b1;              k1 = c1 ? (kt_) : k1; }

    // 2 independent 3-chains, issue-interleaved A/B
#define COMPT(s, ttv) { const int k0_ = (ttv) * 16;                      \
        f32x4 aA = se_##s; f32x4 aB = {0.f, 0.f, 0.f, 0.f};              \
        aA = __builtin_amdgcn_mfma_f32_16x16x32_bf16(ah0_##s, mh0, aA, 0, 0, 0); \
        aB = __builtin_amdgcn_mfma_f32_16x16x32_bf16(ah1_##s, mh1, aB, 0, 0, 0); \
        aA = __builtin_amdgcn_mfma_f32_16x16x32_bf16(al0_##s, mh0, aA, 0, 0, 0); \
        aB = __builtin_amdgcn_mfma_f32_16x16x32_bf16(al1_##s, mh1, aB, 0, 0, 0); \
        aA = __builtin_amdgcn_mfma_f32_16x16x32_bf16(ah0_##s, ml0, aA, 0, 0, 0); \
        aB = __builtin_amdgcn_mfma_f32_16x16x32_bf16(ah1_##s, ml1, aB, 0, 0, 0); \
        { const float d0_ = aA[0] + aB[0]; INS1(d0_, k0_ + kv)     }     \
        { const float d1_ = aA[1] + aB[1]; INS1(d1_, k0_ + kv + 1) }     \
        { const float d2_ = aA[2] + aB[2]; INS1(d2_, k0_ + kv + 2) }     \
        { const float d3_ = aA[3] + aB[3]; INS1(d3_, k0_ + kv + 3) } }

    LOADT(a, 0) LOADT(b, 1)
    for (int tt = 0; tt < 64; tt += 4) {
        LOADT(c, tt + 2) LOADT(d, tt + 3)
        COMPT(a, tt)     COMPT(b, tt + 1)
        LOADT(a, tt + 4) LOADT(b, tt + 5)
        COMPT(c, tt + 2) COMPT(d, tt + 3)
    }
#undef LOADT
#undef INS1
#undef COMPT

    cand[n * 4 + g] = (unsigned int)k1 | ((unsigned int)k2 << 16);
}

// Exact rescore of the 8 candidates per n + histogram + indices output (hist_kernel merged).
// Bit-identical chain to the reference: zx = 2z; a_k = ascending-c fmaf chain;
// sx = pairwise 8-acc of fl(z^2); d = fl(fl(sx + se_k) - a_k).
// Min via ordered-u64 key (d bits || k): first-min semantics.
__global__ void rescore_kernel(const float* __restrict__ z, const float* __restrict__ cb,
                               const float* __restrict__ se,
                               const unsigned int* __restrict__ cand,
                               unsigned long long* __restrict__ keys,
                               int* __restrict__ hist, float* __restrict__ outIdxF) {
    __shared__ int lh[KBOOK];
    for (int i = threadIdx.x; i < KBOOK; i += 256) lh[i] = 0;
    __syncthreads();

    const int n = blockIdx.x * 256 + threadIdx.x;   // grid 256x256
    int ks[8];
#pragma unroll
    for (int g = 0; g < 4; ++g) {
        const unsigned int p = cand[n * 4 + g];
        ks[2 * g]     = (int)(p & 0xFFFFu);
        ks[2 * g + 1] = (int)(p >> 16);
    }
    const int b = n >> 10, hw = n & 1023;
    const float* zb = z + (size_t)b * (CDIM * 1024) + hw;

    float zx[64], r[8];
#pragma unroll
    for (int j = 0; j < 8; ++j) {
        const float zc = zb[j * 1024];
        zx[j] = zc + zc;
        r[j] = __fmul_rn(zc, zc);
    }
#pragma unroll
    for (int c = 8; c < 64; ++c) {
        const float zc = zb[c * 1024];
        zx[c] = zc + zc;
        r[c & 7] = __fadd_rn(r[c & 7], __fmul_rn(zc, zc));
    }
    const float sx = __fadd_rn(__fadd_rn(__fadd_rn(r[0], r[1]), __fadd_rn(r[2], r[3])),
                               __fadd_rn(__fadd_rn(r[4], r[5]), __fadd_rn(r[6], r[7])));

    float a[8];
#pragma unroll
    for (int i = 0; i < 8; ++i) a[i] = 0.0f;
    const float4* cb4 = (const float4*)cb;
#pragma unroll
    for (int q = 0; q < 16; ++q) {               // c = 4q .. 4q+3, ascending per chain
#pragma unroll
        for (int i = 0; i < 8; ++i) {
            const float4 ev = cb4[ks[i] * 16 + q];
            a[i] = fmaf(zx[4 * q],     ev.x, a[i]);
            a[i] = fmaf(zx[4 * q + 1], ev.y, a[i]);
            a[i] = fmaf(zx[4 * q + 2], ev.z, a[i]);
            a[i] = fmaf(zx[4 * q + 3], ev.w, a[i]);
        }
    }
    unsigned long long best = ~0ull;
#pragma unroll
    for (int i = 0; i < 8; ++i) {
        const float d = __fsub_rn(__fadd_rn(sx, se[ks[i]]), a[i]);
        unsigned int ob = __float_as_uint(d);
        ob = (ob & 0x80000000u) ? ~ob : (ob | 0x80000000u);
        const unsigned long long key = ((unsigned long long)ob << 32) | (unsigned int)ks[i];
        if (key < best) best = key;
    }
    keys[n] = best;    // single writer: plain store
    const int kbest = (int)(best & 0xFFFFFFFFu);
    outIdxF[n] = (float)kbest;
    atomicAdd(&lh[kbest], 1);
    __syncthreads();
    for (int i = threadIdx.x; i < KBOOK; i += 256)
        if (lh[i]) atomicAdd(&hist[i], lh[i]);
}

// quantized_z = cb[idx]; quantized_z_st = fl(z + fl(q - z)); float4-vectorized.
// Block 0 additionally computes perplexity (hist complete: rescore finished before
// this kernel launched, stream order).  perp_kernel merged here.
__global__ void scatter_kernel(const float* __restrict__ z, const float* __restrict__ cb,
                               const unsigned long long* __restrict__ keys,
                               const int* __restrict__ hist,
                               float* __restrict__ out) {
    const int o = (blockIdx.x * 256 + threadIdx.x) * 4;    // [0, NTOT), step 4
    const int b = o >> 16, c = (o >> 10) & 63, hw = o & 1023;
    const int n = (b << 10) | hw;
    float q[4];
#pragma unroll
    for (int j = 0; j < 4; ++j) {
        const int k = (int)(keys[n + j] & 0xFFFFFFFFu);
        q[j] = cb[k * CDIM + c];
    }
    const float4 zv = *(const float4*)(z + o);
    *(float4*)(out + o) = make_float4(q[0], q[1], q[2], q[3]);
    float4 st;
    st.x = __fadd_rn(zv.x, __fsub_rn(q[0], zv.x));
    st.y = __fadd_rn(zv.y, __fsub_rn(q[1], zv.y));
    st.z = __fadd_rn(zv.z, __fsub_rn(q[2], zv.z));
    st.w = __fadd_rn(zv.w, __fsub_rn(q[3], zv.w));
    *(float4*)(out + NTOT + o) = st;

    if (blockIdx.x == 0) {
        __shared__ double partial[4];
        const int t = threadIdx.x;        // 256 threads x 4 hist entries
        double term = 0.0;
#pragma unroll
        for (int j = 0; j < 4; ++j) {
            const int cnt = hist[t + 256 * j];
            if (cnt > 0) { const double p = (double)cnt / (double)NVEC; term += p * log(p); }
        }
        for (int off = 32; off > 0; off >>= 1) term += __shfl_down(term, off);
        if ((t & 63) == 0) partial[t >> 6] = term;
        __syncthreads();
        if (t == 0) {
            const double s = partial[0] + partial[1] + partial[2] + partial[3];
            out[2 * NTOT + NVEC] = (float)exp(-s);
        }
    }
}

extern "C" void kernel_launch(void* const* d_in, const int* in_sizes, int n_in,
                              void* d_out, int out_size, void* d_ws, size_t ws_size,
                              hipStream_t stream) {
    const float* z  = (const float*)d_in[0];   // [64,64,32,32]
    const float* cb = (const float*)d_in[1];   // [1024,64]
    float* out = (float*)d_out;

    char* ws = (char*)d_ws;
    unsigned long long* keys = (unsigned long long*)(ws + 0);
    float* se   = (float*)(ws + 524288);
    int*   hist = (int*)(ws + 528384);

    // Transient scratch inside d_out's quantized_z region (overwritten by scatter later).
    char* outB = (char*)d_out;
    unsigned int* cand = (unsigned int*)(outB);                         // 1 MB
    __bf16* cbT = (__bf16*)(outB + (1 << 20));                          // 256 KB

    prep_kernel<<<4, 256, 0, stream>>>(cb, se, hist, cbT);
    approx_kernel<<<NVEC / 64, 256, 0, stream>>>(z, cbT, se, cand);
    rescore_kernel<<<NVEC / 256, 256, 0, stream>>>(z, cb, se, cand, keys, hist, out + 2 * NTOT);
    scatter_kernel<<<NTOT / 1024, 256, 0, stream>>>(z, cb, keys, hist, out);
}